// Round 11
// baseline (596.691 us; speedup 1.0000x reference)
//
#include <hip/hip_runtime.h>
#include <math.h>

#define NP 4096      // N = M
#define NCP 512      // NC = MC
#define HD 256       // H and CF
#define CCD 1024     // CC
#define SPOTK 16
#define DOWNK 8
#define SEEDN 128
#define JCH 512      // seed rank j-chunk
#define NJC (NP / JCH)

// ---------------------------------------------------------------------------
// Scores GEMM + fused softmax partial stats.  (BK=32; see R9/R10 notes --
// structure is issue-mix-bound at ~38% fp32 peak; left as-is.)
// ---------------------------------------------------------------------------
__global__ __launch_bounds__(256) void gemm128_bt(
    const float* __restrict__ A, const float* __restrict__ B,
    float* __restrict__ C,
    float* __restrict__ pmaxR, float* __restrict__ psumR,
    float* __restrict__ pmaxC, float* __restrict__ psumC,
    int M, int N, int K)
{
    const int PAD = 132;
    __shared__ float As[32 * 132];
    __shared__ float Bs[32 * 132];

    const int bm = blockIdx.y * 128, bn = blockIdx.x * 128;
    const int t = threadIdx.x;
    const int tx = t & 15, ty = t >> 4;

    float acc[2][2][4][4] = {};

    for (int k0 = 0; k0 < K; k0 += 32) {
#pragma unroll
        for (int it = 0; it < 4; it++) {
            int idx = t + it * 256;
            int row = idx >> 3, kc = (idx & 7) * 4;
            float4 va = *(const float4*)&A[(size_t)(bm + row) * K + k0 + kc];
            As[(kc + 0) * PAD + row] = va.x;
            As[(kc + 1) * PAD + row] = va.y;
            As[(kc + 2) * PAD + row] = va.z;
            As[(kc + 3) * PAD + row] = va.w;
            float4 vb = *(const float4*)&B[(size_t)(bn + row) * K + k0 + kc];
            Bs[(kc + 0) * PAD + row] = vb.x;
            Bs[(kc + 1) * PAD + row] = vb.y;
            Bs[(kc + 2) * PAD + row] = vb.z;
            Bs[(kc + 3) * PAD + row] = vb.w;
        }
        __syncthreads();
#pragma unroll
        for (int kk = 0; kk < 32; kk++) {
            float4 a0 = *(const float4*)&As[kk * PAD + ty * 4];
            float4 a1 = *(const float4*)&As[kk * PAD + ty * 4 + 64];
            float4 b0 = *(const float4*)&Bs[kk * PAD + tx * 4];
            float4 b1 = *(const float4*)&Bs[kk * PAD + tx * 4 + 64];
            float ar[2][4] = {{a0.x, a0.y, a0.z, a0.w}, {a1.x, a1.y, a1.z, a1.w}};
            float br[2][4] = {{b0.x, b0.y, b0.z, b0.w}, {b1.x, b1.y, b1.z, b1.w}};
#pragma unroll
            for (int qr = 0; qr < 2; qr++)
#pragma unroll
                for (int qc = 0; qc < 2; qc++)
#pragma unroll
                    for (int i = 0; i < 4; i++)
#pragma unroll
                        for (int j = 0; j < 4; j++)
                            acc[qr][qc][i][j] = fmaf(ar[qr][i], br[qc][j], acc[qr][qc][i][j]);
        }
        __syncthreads();
    }

    // C write (unchanged order -> bitwise-identical scores)
#pragma unroll
    for (int qr = 0; qr < 2; qr++)
#pragma unroll
        for (int i = 0; i < 4; i++) {
            int m = bm + qr * 64 + ty * 4 + i;
#pragma unroll
            for (int qc = 0; qc < 2; qc++) {
                int n = bn + qc * 64 + tx * 4;
                float4 v = make_float4(acc[qr][qc][i][0], acc[qr][qc][i][1],
                                       acc[qr][qc][i][2], acc[qr][qc][i][3]);
                *(float4*)&C[(size_t)m * N + n] = v;
            }
        }

    // ---- row partials ----
#pragma unroll
    for (int qr = 0; qr < 2; qr++)
#pragma unroll
        for (int i = 0; i < 4; i++) {
            float m = -INFINITY;
#pragma unroll
            for (int qc = 0; qc < 2; qc++)
#pragma unroll
                for (int j = 0; j < 4; j++) m = fmaxf(m, acc[qr][qc][i][j]);
            float s = 0.f;
#pragma unroll
            for (int qc = 0; qc < 2; qc++)
#pragma unroll
                for (int j = 0; j < 4; j++) s += expf(acc[qr][qc][i][j] - m);
#pragma unroll
            for (int off = 1; off < 16; off <<= 1) {
                float om = __shfl_xor(m, off), os = __shfl_xor(s, off);
                float Mx = fmaxf(m, om);
                s = s * expf(m - Mx) + os * expf(om - Mx);
                m = Mx;
            }
            if (tx == 0) {
                int r = bm + qr * 64 + ty * 4 + i;
                pmaxR[(size_t)blockIdx.x * NP + r] = m;
                psumR[(size_t)blockIdx.x * NP + r] = s;
            }
        }

    // ---- col partials ----
    float* colm = As;
    float* cols_ = Bs;
#pragma unroll
    for (int qc = 0; qc < 2; qc++)
#pragma unroll
        for (int j = 0; j < 4; j++) {
            float m = -INFINITY;
#pragma unroll
            for (int qr = 0; qr < 2; qr++)
#pragma unroll
                for (int i = 0; i < 4; i++) m = fmaxf(m, acc[qr][qc][i][j]);
            float s = 0.f;
#pragma unroll
            for (int qr = 0; qr < 2; qr++)
#pragma unroll
                for (int i = 0; i < 4; i++) s += expf(acc[qr][qc][i][j] - m);
#pragma unroll
            for (int off = 16; off < 64; off <<= 1) {
                float om = __shfl_xor(m, off), os = __shfl_xor(s, off);
                float Mx = fmaxf(m, om);
                s = s * expf(m - Mx) + os * expf(om - Mx);
                m = Mx;
            }
            if ((ty & 3) == 0) {
                int w = ty >> 2, c = qc * 64 + tx * 4 + j;
                colm[w * 132 + c] = m;
                cols_[w * 132 + c] = s;
            }
        }
    __syncthreads();
    if (t < 128) {
        int c = t;
        float m = colm[c], s = cols_[c];
#pragma unroll
        for (int w = 1; w < 4; w++) {
            float om = colm[w * 132 + c], os = cols_[w * 132 + c];
            float Mx = fmaxf(m, om);
            s = s * expf(m - Mx) + os * expf(om - Mx);
            m = Mx;
        }
        pmaxC[(size_t)blockIdx.y * NP + bn + c] = m;
        psumC[(size_t)blockIdx.y * NP + bn + c] = s;
    }
}

// Partial-stats combine over 32 chunks: out(max, rescaled-sum). z-batched.
__global__ __launch_bounds__(256) void combine_stats(
    const float* __restrict__ pmaxA, const float* __restrict__ psumA,
    const float* __restrict__ pmaxB, const float* __restrict__ psumB,
    float* omaxA, float* osumA, float* omaxB, float* osumB)
{
    const float* pmax = blockIdx.z ? pmaxB : pmaxA;
    const float* psum = blockIdx.z ? psumB : psumA;
    float* omax       = blockIdx.z ? omaxB : omaxA;
    float* osum       = blockIdx.z ? osumB : osumA;
    int m = blockIdx.x * 256 + threadIdx.x;
    float mx = -INFINITY;
    for (int c = 0; c < 32; c++) mx = fmaxf(mx, pmax[(size_t)c * NP + m]);
    float sum = 0.f;
    for (int c = 0; c < 32; c++) sum += psum[(size_t)c * NP + m] * expf(pmax[(size_t)c * NP + m] - mx);
    omax[m] = mx; osum[m] = sum;
}

// ---------------------------------------------------------------------------
// Projection GEMM, 64x64 tile, 256 threads, 4x4 microtile: C = A @ B (+bias).
// ---------------------------------------------------------------------------
__global__ __launch_bounds__(256) void gemm64(
    const float* __restrict__ A0, const float* __restrict__ A1,
    const float* __restrict__ B, const float* __restrict__ bias,
    float* __restrict__ C0, float* __restrict__ C1,
    int M, int N, int K)
{
    const float* A = blockIdx.z ? A1 : A0;
    float* C = blockIdx.z ? C1 : C0;

    const int PAD = 68;
    __shared__ float As[16 * 68];
    __shared__ float Bs[16 * 68];

    const int bm = blockIdx.y * 64, bn = blockIdx.x * 64;
    const int t = threadIdx.x;
    const int tx = t & 15, ty = t >> 4;

    float acc[4][4] = {};

    for (int k0 = 0; k0 < K; k0 += 16) {
        {
            int row = t >> 2, kc = (t & 3) * 4;
            float4 v = *(const float4*)&A[(size_t)(bm + row) * K + k0 + kc];
            As[(kc + 0) * PAD + row] = v.x;
            As[(kc + 1) * PAD + row] = v.y;
            As[(kc + 2) * PAD + row] = v.z;
            As[(kc + 3) * PAD + row] = v.w;
        }
        {
            int k = t >> 4, n4 = (t & 15) * 4;
            float4 v = *(const float4*)&B[(size_t)(k0 + k) * N + bn + n4];
            *(float4*)&Bs[k * PAD + n4] = v;
        }
        __syncthreads();
#pragma unroll
        for (int kk = 0; kk < 16; kk++) {
            float4 a4 = *(const float4*)&As[kk * PAD + ty * 4];
            float4 b4 = *(const float4*)&Bs[kk * PAD + tx * 4];
            float ar[4] = {a4.x, a4.y, a4.z, a4.w};
            float br[4] = {b4.x, b4.y, b4.z, b4.w};
#pragma unroll
            for (int i = 0; i < 4; i++)
#pragma unroll
                for (int j = 0; j < 4; j++)
                    acc[i][j] = fmaf(ar[i], br[j], acc[i][j]);
        }
        __syncthreads();
    }
    float4 b4 = *(const float4*)&bias[bn + tx * 4];
#pragma unroll
    for (int i = 0; i < 4; i++) {
        int m = bm + ty * 4 + i;
        float4 v = make_float4(acc[i][0] + b4.x, acc[i][1] + b4.y,
                               acc[i][2] + b4.z, acc[i][3] + b4.w);
        *(float4*)&C[(size_t)m * N + bn + tx * 4] = v;
    }
}

// Split-K variant: z = pair*8 + ks; atomicAdd 64x64 partials into C
// (pre-initialized with bias via pack_pts z=4/5).
__global__ __launch_bounds__(256) void gemm64_atomic(
    const float* __restrict__ A0, const float* __restrict__ A1,
    const float* __restrict__ B,
    float* __restrict__ C0, float* __restrict__ C1,
    int M, int N, int K, int KCH)
{
    int pair = blockIdx.z >> 3, ks = blockIdx.z & 7;
    const float* A = pair ? A1 : A0;
    float* C = pair ? C1 : C0;

    const int PAD = 68;
    __shared__ float As[16 * 68];
    __shared__ float Bs[16 * 68];

    const int bm = blockIdx.y * 64, bn = blockIdx.x * 64;
    const int t = threadIdx.x;
    const int tx = t & 15, ty = t >> 4;
    const int kbeg = ks * KCH, kend = kbeg + KCH;

    float acc[4][4] = {};

    for (int k0 = kbeg; k0 < kend; k0 += 16) {
        {
            int row = t >> 2, kc = (t & 3) * 4;
            float4 v = *(const float4*)&A[(size_t)(bm + row) * K + k0 + kc];
            As[(kc + 0) * PAD + row] = v.x;
            As[(kc + 1) * PAD + row] = v.y;
            As[(kc + 2) * PAD + row] = v.z;
            As[(kc + 3) * PAD + row] = v.w;
        }
        {
            int k = t >> 4, n4 = (t & 15) * 4;
            float4 v = *(const float4*)&B[(size_t)(k0 + k) * N + bn + n4];
            *(float4*)&Bs[k * PAD + n4] = v;
        }
        __syncthreads();
#pragma unroll
        for (int kk = 0; kk < 16; kk++) {
            float4 a4 = *(const float4*)&As[kk * PAD + ty * 4];
            float4 b4 = *(const float4*)&Bs[kk * PAD + tx * 4];
            float ar[4] = {a4.x, a4.y, a4.z, a4.w};
            float br[4] = {b4.x, b4.y, b4.z, b4.w};
#pragma unroll
            for (int i = 0; i < 4; i++)
#pragma unroll
                for (int j = 0; j < 4; j++)
                    acc[i][j] = fmaf(ar[i], br[j], acc[i][j]);
        }
        __syncthreads();
    }
#pragma unroll
    for (int i = 0; i < 4; i++) {
        int m = bm + ty * 4 + i;
#pragma unroll
        for (int j = 0; j < 4; j++)
            atomicAdd(&C[(size_t)m * N + bn + tx * 4 + j], acc[i][j]);
    }
}

// ---------------------------------------------------------------------------
// Pack points (z=0..3) + hc bias pre-fill (z=4,5; grid-stride).
// ---------------------------------------------------------------------------
__global__ void pack_pts(const float* __restrict__ p0, const float* __restrict__ p1,
                         const float* __restrict__ p2, const float* __restrict__ p3,
                         const float* __restrict__ b1,
                         float4* o0, float4* o1, float4* o2, float4* o3,
                         float* __restrict__ o_hcr, float* __restrict__ o_hcs)
{
    int z = blockIdx.z;
    if (z >= 4) {
        float* o = (z == 4) ? o_hcr : o_hcs;
        for (int idx = blockIdx.x * 256 + threadIdx.x; idx < NCP * HD; idx += 16 * 256)
            o[idx] = b1[idx & (HD - 1)];
        return;
    }
    const float* p = (z == 0) ? p0 : (z == 1) ? p1 : (z == 2) ? p2 : p3;
    float4* o      = (z == 0) ? o0 : (z == 1) ? o1 : (z == 2) ? o2 : o3;
    int n = (z < 2) ? NP : NCP;
    int i = blockIdx.x * 256 + threadIdx.x;
    if (i >= n) return;
    float x = p[i * 3], y = p[i * 3 + 1], zz = p[i * 3 + 2];
    o[i] = make_float4(x, y, zz, x * x + y * y + zz * zz);
}

// ---------------------------------------------------------------------------
// Fused finalize: final scores in place + row-argmax partials (lex) +
// col-argmax partials.  Grid (4 colchunks x 64 rowchunks), 256 threads,
// thread = 4 consecutive cols.  Same per-element sc expression/order as the
// old finalize_rows -> s bitwise identical; argmax semantics identical
// (strict > ascending + (val desc, idx asc) lex).
// ---------------------------------------------------------------------------
__global__ __launch_bounds__(256) void finalize_fused(
    float* __restrict__ s,
    const float* __restrict__ rmax, const float* __restrict__ rsum,
    const float* __restrict__ cmax, const float* __restrict__ csum,
    float* __restrict__ rowpV, int* __restrict__ rowpI,
    float* __restrict__ colV, int* __restrict__ colI)
{
    int tid = threadIdx.x;
    int bc = blockIdx.x;                 // col chunk (1024 cols)
    int br = blockIdx.y;                 // row chunk (64 rows)
    int c = bc * 1024 + tid * 4;
    int lane = tid & 63, wid = tid >> 6;

    float4 cm4 = *(const float4*)&cmax[c];
    float4 cs4 = *(const float4*)&csum[c];
    float cv[4] = {-INFINITY, -INFINITY, -INFINITY, -INFINITY};
    int   ci[4] = {0, 0, 0, 0};

    __shared__ float rv[4]; __shared__ int ri[4];

    for (int r = 0; r < 64; r++) {
        int row = br * 64 + r;
        float rm = rmax[row], rs = rsum[row];
        float4 v = *(const float4*)&s[(size_t)row * NP + c];
        float sc[4];
        {
            float a0 = expf(v.x - rm) / rs, b0 = expf(v.x - cm4.x) / cs4.x; sc[0] = a0 * b0;
            float a1 = expf(v.y - rm) / rs, b1_ = expf(v.y - cm4.y) / cs4.y; sc[1] = a1 * b1_;
            float a2 = expf(v.z - rm) / rs, b2_ = expf(v.z - cm4.z) / cs4.z; sc[2] = a2 * b2_;
            float a3 = expf(v.w - rm) / rs, b3_ = expf(v.w - cm4.w) / cs4.w; sc[3] = a3 * b3_;
        }
        *(float4*)&s[(size_t)row * NP + c] = make_float4(sc[0], sc[1], sc[2], sc[3]);

        // col running argmax (ascending row, strict >)
#pragma unroll
        for (int j = 0; j < 4; j++)
            if (sc[j] > cv[j]) { cv[j] = sc[j]; ci[j] = row; }

        // row argmax: thread best over 4 ascending cols
        float bv = sc[0]; int bi = c;
#pragma unroll
        for (int j = 1; j < 4; j++)
            if (sc[j] > bv) { bv = sc[j]; bi = c + j; }
        // wave lex reduce
#pragma unroll
        for (int off = 1; off < 64; off <<= 1) {
            float ov = __shfl_xor(bv, off); int oi = __shfl_xor(bi, off);
            if (ov > bv || (ov == bv && oi < bi)) { bv = ov; bi = oi; }
        }
        if (lane == 0) { rv[wid] = bv; ri[wid] = bi; }
        __syncthreads();
        if (tid == 0) {
            float gv = rv[0]; int gi = ri[0];
#pragma unroll
            for (int w = 1; w < 4; w++) {
                float ov = rv[w]; int oi = ri[w];
                if (ov > gv || (ov == gv && oi < gi)) { gv = ov; gi = oi; }
            }
            rowpV[(size_t)bc * NP + row] = gv;
            rowpI[(size_t)bc * NP + row] = gi;
        }
        __syncthreads();
    }

    *(float4*)&colV[(size_t)br * NP + c] = make_float4(cv[0], cv[1], cv[2], cv[3]);
    *(int4*)&colI[(size_t)br * NP + c]   = make_int4(ci[0], ci[1], ci[2], ci[3]);
}

// Combine argmax partials: z=0 rows (4 chunks, lex), z=1 cols (64 chunks).
__global__ __launch_bounds__(256) void argmax_combine(
    const float* __restrict__ rowpV, const int* __restrict__ rowpI,
    const float* __restrict__ colV, const int* __restrict__ colI,
    float* __restrict__ confr, int* __restrict__ mir,
    float* __restrict__ confs, int* __restrict__ mis)
{
    int i = blockIdx.x * 256 + threadIdx.x;
    if (blockIdx.z == 0) {
        float best = -INFINITY; int bi = 0x7fffffff;
#pragma unroll
        for (int ch = 0; ch < 4; ch++) {
            float v = rowpV[(size_t)ch * NP + i];
            int  ix = rowpI[(size_t)ch * NP + i];
            if (v > best || (v == best && ix < bi)) { best = v; bi = ix; }
        }
        confr[i] = best; mir[i] = bi;
    } else {
        float best = -INFINITY; int bi = 0;
        for (int ch = 0; ch < 64; ch++) {
            float v = colV[(size_t)ch * NP + i];
            if (v > best) { best = v; bi = colI[(size_t)ch * NP + i]; }
        }
        confs[i] = best; mis[i] = bi;
    }
}

// Gathers after argmax (z-batched 0..3)
__global__ void gather_spot(
    const float4* __restrict__ sp4, const float4* __restrict__ rp4,
    const int* __restrict__ sidx16, const int* __restrict__ ridx16,
    const int* __restrict__ mir, const int* __restrict__ mis,
    float4* __restrict__ qr, float4* __restrict__ qs,
    float* __restrict__ o_spotr, float* __restrict__ o_spots)
{
    int z = blockIdx.z;
    int t = blockIdx.x * 256 + threadIdx.x;
    if (z < 2) {
        if (t >= NP) return;
        const float4* p4 = z ? rp4 : sp4;
        const int*    mi = z ? mis : mir;
        float4*       q  = z ? qs : qr;
        q[t] = p4[mi[t]];
    } else {
        int n = t >> 4, k = t & 15;
        const int* idx16 = (z == 2) ? sidx16 : ridx16;
        const int* mi    = (z == 2) ? mir : mis;
        float* outp      = (z == 2) ? o_spotr : o_spots;
        outp[t] = (float)idx16[(size_t)mi[n] * SPOTK + k];
    }
}

// compat[n] = mean_j relu(1 - |d(base_n, base_j) - d(q_n, q_j)| / 3)   (z-batched)
__global__ __launch_bounds__(256) void compat_kernel(
    const float4* __restrict__ baseA, const float4* __restrict__ baseB,
    const float4* __restrict__ qA, const float4* __restrict__ qB,
    float* __restrict__ o1A, float* __restrict__ o1B,
    float* __restrict__ o2A, float* __restrict__ o2B)
{
    const float4* base = blockIdx.z ? baseB : baseA;
    const float4* q    = blockIdx.z ? qB : qA;
    float* out1        = blockIdx.z ? o1B : o1A;
    float* out2        = blockIdx.z ? o2B : o2A;
    int n = blockIdx.x;
    float4 b = base[n];
    float4 a = q[n];
    float sum = 0.f;
    for (int j = threadIdx.x; j < NP; j += 256) {
        float4 p = base[j];
        float rt = b.x * p.x + b.y * p.y + b.z * p.z;
        float rd = (b.w - 2.f * rt) + p.w;
        float4 qj = q[j];
        float st = a.x * qj.x + a.y * qj.y + a.z * qj.z;
        float sd = (a.w - 2.f * st) + qj.w;
        float c = 1.f - fabsf(rd - sd) / 3.0f;
        sum += fmaxf(c, 0.f);
    }
    __shared__ float red[256];
    red[threadIdx.x] = sum; __syncthreads();
    for (int off = 128; off; off >>= 1) {
        if (threadIdx.x < off) red[threadIdx.x] += red[threadIdx.x + off];
        __syncthreads();
    }
    if (threadIdx.x == 0) { float c = red[0] * (1.0f / NP); out1[n] = c; out2[n] = c; }
}

// ---------------------------------------------------------------------------
// Seeding, parallel rank pipeline (exact jax.lax.top_k order/ties).
// ---------------------------------------------------------------------------
__global__ __launch_bounds__(256) void seed_prep(
    const float* __restrict__ compatA, const float* __restrict__ compatB,
    const float* __restrict__ confA, const float* __restrict__ confB,
    float* __restrict__ wA, float* __restrict__ wB)
{
    const float* compat = blockIdx.z ? compatB : compatA;
    const float* conf   = blockIdx.z ? confB : confA;
    float* w            = blockIdx.z ? wB : wA;
    __shared__ float red[256];
    int tid = threadIdx.x;
    float mx = -INFINITY;
    for (int j = tid; j < NP; j += 256) mx = fmaxf(mx, compat[j]);
    red[tid] = mx; __syncthreads();
    for (int off = 128; off; off >>= 1) {
        if (tid < off) red[tid] = fmaxf(red[tid], red[tid + off]);
        __syncthreads();
    }
    float thr = red[0] * 0.5f;
    for (int j = tid; j < NP; j += 256) {
        float c = compat[j];
        w[j] = (c < thr) ? conf[j] * c : 0.0f;
    }
}

__global__ __launch_bounds__(256) void seed_rank_partial(
    const float* __restrict__ wA, const float* __restrict__ wB,
    int* __restrict__ rankpA, int* __restrict__ rankpB)
{
    const float* w = blockIdx.z ? wB : wA;
    int* rankp     = blockIdx.z ? rankpB : rankpA;
    int tid = threadIdx.x;
    int jc = blockIdx.y;

    __shared__ float4 wj[JCH / 4];
    if (tid < JCH / 4) wj[tid] = ((const float4*)w)[jc * (JCH / 4) + tid];
    __syncthreads();

    int i = blockIdx.x * 256 + tid;
    float wi = w[i];
    int jbase = jc * JCH;
    int r0 = 0, r1 = 0, r2 = 0, r3 = 0;
#pragma unroll 4
    for (int j4 = 0; j4 < JCH / 4; j4++) {
        float4 v = wj[j4];
        int j = jbase + j4 * 4;
        r0 += (v.x > wi || (v.x == wi && (j    ) < i));
        r1 += (v.y > wi || (v.y == wi && (j + 1) < i));
        r2 += (v.z > wi || (v.z == wi && (j + 2) < i));
        r3 += (v.w > wi || (v.w == wi && (j + 3) < i));
    }
    rankp[(size_t)jc * NP + i] = (r0 + r1) + (r2 + r3);
}

__global__ __launch_bounds__(256) void seed_scatter(
    const int* __restrict__ rankpA, const int* __restrict__ rankpB,
    float* __restrict__ outA, float* __restrict__ outB)
{
    const int* rankp = blockIdx.z ? rankpB : rankpA;
    float* outp      = blockIdx.z ? outB : outA;
    int i = blockIdx.x * 256 + threadIdx.x;
    int r = 0;
#pragma unroll
    for (int jc = 0; jc < NJC; jc++) r += rankp[(size_t)jc * NP + i];
    if (r < SEEDN) outp[r] = (float)i;
}

// ---------------------------------------------------------------------------
// Wave-wide bitonic sorts via shfl_xor (64 lanes, zero barriers).
// ---------------------------------------------------------------------------
__device__ __forceinline__ void bitonic64_val(float& d, int lane)
{
#pragma unroll
    for (int k = 2; k <= 64; k <<= 1)
#pragma unroll
        for (int j = k >> 1; j > 0; j >>= 1) {
            float od = __shfl_xor(d, j);
            bool lower = ((lane & j) == 0);
            bool asc   = ((lane & k) == 0);
            bool take = (lower == asc) ? (od < d) : (d < od);
            d = take ? od : d;
        }
}

__device__ __forceinline__ void bitonic64_lex(float& d, int& i, int lane)
{
#pragma unroll
    for (int k = 2; k <= 64; k <<= 1)
#pragma unroll
        for (int j = k >> 1; j > 0; j >>= 1) {
            float od = __shfl_xor(d, j);
            int   oi = __shfl_xor(i, j);
            bool lower = ((lane & j) == 0);
            bool asc   = ((lane & k) == 0);
            bool less = (od < d) || (od == d && oi < i);
            bool gtr  = (d < od) || (d == od && i < oi);
            bool take = (lower == asc) ? less : gtr;
            d = take ? od : d;
            i = take ? oi : i;
        }
}

template<int KSEL>
__device__ __forceinline__ void merge_chunk(float& run_d, int& run_i,
                                            float cd, int ci, int lane)
{
    bitonic64_lex(cd, ci, lane);
    int src = lane - KSEL;
    int s2 = (src >= 0 && src < KSEL) ? src : 0;
    float cd2 = __shfl(cd, s2);
    int   ci2 = __shfl(ci, s2);
    float nd = (lane < KSEL) ? run_d : ((lane < 2 * KSEL) ? cd2 : INFINITY);
    int   ni = (lane < KSEL) ? run_i : ((lane < 2 * KSEL) ? ci2 : 0x7fffffff);
    bitonic64_lex(nd, ni, lane);
    run_d = nd; run_i = ni;
}

// ---------------------------------------------------------------------------
// KNN top-K via threshold pre-filter (packed float4 points).
// ---------------------------------------------------------------------------
template<int KSEL>
__global__ __launch_bounds__(256) void knn_topk(
    const float4* __restrict__ rowA, const float4* __restrict__ rowB,
    const float4* __restrict__ colA, const float4* __restrict__ colB,
    int ncols,
    int* __restrict__ outiA, int* __restrict__ outiB,
    float* __restrict__ outfA, float* __restrict__ outfB)
{
    const float4* rowp = blockIdx.z ? rowB : rowA;
    const float4* colp = blockIdx.z ? colB : colA;
    int* outi = blockIdx.z ? outiB : outiA;
    float* outf = blockIdx.z ? outfB : outfA;

    int wid = threadIdx.x >> 6, lane = threadIdx.x & 63;
    int r = blockIdx.x * 4 + wid;

    float4 p = rowp[r];

    float mn = INFINITY;
    for (int j0 = 0; j0 < ncols; j0 += 64) {
        float4 c = colp[j0 + lane];
        float t = p.x * c.x + p.y * c.y + p.z * c.z;
        float d = (p.w - 2.f * t) + c.w;
        mn = fminf(mn, d);
    }
    bitonic64_val(mn, lane);
    float T = __shfl(mn, KSEL - 1) + 1e-4f;

    __shared__ float qd[4][256];
    __shared__ int   qi[4][256];
    int cnt = 0; bool ovf = false;
    for (int j0 = 0; j0 < ncols; j0 += 64) {
        int j = j0 + lane;
        float4 c = colp[j];
        float t = p.x * c.x + p.y * c.y + p.z * c.z;
        float d = (p.w - 2.f * t) + c.w;
        bool keep = (d <= T);
        unsigned long long mask = __ballot(keep);
        int nsel = __popcll(mask);
        if (cnt + nsel > 256) { ovf = true; break; }
        if (keep) {
            int pos = cnt + (int)__popcll(mask & ((1ull << lane) - 1ull));
            qd[wid][pos] = d; qi[wid][pos] = j;
        }
        cnt += nsel;
    }

    float run_d = INFINITY; int run_i = 0x7fffffff;
    if (!ovf) {
        for (int c = 0; c < cnt; c += 64) {
            int idx = c + lane;
            float cd = (idx < cnt) ? qd[wid][idx] : INFINITY;
            int   ci = (idx < cnt) ? qi[wid][idx] : 0x7fffffff;
            merge_chunk<KSEL>(run_d, run_i, cd, ci, lane);
        }
    } else {
        for (int j0 = 0; j0 < ncols; j0 += 64) {
            int j = j0 + lane;
            float4 c = colp[j];
            float t = p.x * c.x + p.y * c.y + p.z * c.z;
            float d = (p.w - 2.f * t) + c.w;
            merge_chunk<KSEL>(run_d, run_i, d, j, lane);
        }
    }

    if (lane < KSEL) {
        if (outi) outi[(size_t)r * KSEL + lane] = run_i;
        else      outf[(size_t)r * KSEL + lane] = (float)run_i;
    }
}

// argmin over the 512 coarse points per fine point (first-min index), z-batched
__global__ __launch_bounds__(256) void up_argmin(
    const float4* __restrict__ ptsA, const float4* __restrict__ ptsB,
    const float4* __restrict__ ptscA, const float4* __restrict__ ptscB,
    float* __restrict__ outA, float* __restrict__ outB)
{
    const float4* pts   = blockIdx.z ? ptsB : ptsA;
    const float4* pts_c = blockIdx.z ? ptscB : ptscA;
    float* out_f        = blockIdx.z ? outB : outA;
    __shared__ float4 cp[NCP];
    for (int c = threadIdx.x; c < NCP; c += 256) cp[c] = pts_c[c];
    __syncthreads();
    int n = blockIdx.x * 256 + threadIdx.x;
    float4 p = pts[n];
    float best = INFINITY; int bi = 0;
    for (int c = 0; c < NCP; c++) {
        float4 q = cp[c];
        float t = p.x * q.x + p.y * q.y + p.z * q.z;
        float d = (p.w - 2.f * t) + q.w;
        if (d < best) { best = d; bi = c; }
    }
    out_f[n] = (float)bi;
}

// ---------------------------------------------------------------------------
extern "C" void kernel_launch(void* const* d_in, const int* in_sizes, int n_in,
                              void* d_out, int out_size, void* d_ws, size_t ws_size,
                              hipStream_t stream)
{
    const float* ref_points   = (const float*)d_in[0];
    const float* src_points   = (const float*)d_in[1];
    const float* ref_feats    = (const float*)d_in[2];
    const float* src_feats    = (const float*)d_in[3];
    const float* ref_points_c = (const float*)d_in[4];
    const float* src_points_c = (const float*)d_in[5];
    const float* ref_feats_c  = (const float*)d_in[6];
    const float* src_feats_c  = (const float*)d_in[7];
    const float* W1 = (const float*)d_in[8];
    const float* b1 = (const float*)d_in[9];
    const float* W2 = (const float*)d_in[10];
    const float* b2 = (const float*)d_in[11];

    // ---- d_out layout (all float32; indices written as float) ----
    float* out = (float*)d_out;
    float* o_scores = out;                       // 4096*4096
    float* o_compr  = o_scores + (size_t)NP * NP;
    float* o_comps  = o_compr + NP;
    float* o_seedr  = o_comps + NP;
    float* o_seeds  = o_seedr + SEEDN;
    float* o_spotr  = o_seeds + SEEDN;           // 4096*16
    float* o_spots  = o_spotr + (size_t)NP * SPOTK;
    float* o_hcr    = o_spots + (size_t)NP * SPOTK;   // 512*256
    float* o_hcs    = o_hcr + (size_t)NCP * HD;
    float* o_rup    = o_hcs + (size_t)NCP * HD;  // 4096
    float* o_sup    = o_rup + NP;
    float* o_rdown  = o_sup + NP;                // 512*8
    float* o_sdown  = o_rdown + (size_t)NCP * DOWNK;

    // ---- workspace layout ----
    float* ws = (float*)d_ws;
    float* hfr   = ws;                           // 4096*256
    float* hfs   = hfr + (size_t)NP * HD;
    float* rmax  = hfs + (size_t)NP * HD;        // 4096 each
    float* rsum  = rmax + NP;
    float* cmax  = rsum + NP;
    float* csum  = cmax + NP;
    float* confr = csum + NP;
    float* confs = confr + NP;
    float* compr = confs + NP;
    float* comps = compr + NP;
    int*   mir   = (int*)(comps + NP);
    int*   mis   = mir + NP;
    float* pmax  = (float*)(mis + NP);           // 32*NP (col stats partials; later colV lo)
    float* psum  = pmax + 32 * NP;               // 32*NP (col stats partials; later colV hi)
    float* pconf = psum + 32 * NP;               // 32*NP (row stats partials; later colI lo)
    int*   pmi   = (int*)(pconf + 32 * NP);      // 32*NP (row stats partials; later colI hi)
    float4* qr   = (float4*)(pmi + 32 * NP);     // 4096 float4 each
    float4* qs   = qr + NP;
    int* ridx16  = (int*)(qs + NP);              // 4096*16 each
    int* sidx16  = ridx16 + (size_t)NP * SPOTK;
    float4* rp4  = (float4*)(sidx16 + (size_t)NP * SPOTK);  // packed points
    float4* sp4  = rp4 + NP;
    float4* rcp4 = sp4 + NP;
    float4* scp4 = rcp4 + NCP;
    float* wA    = (float*)(scp4 + NCP);         // seed weights, 4096 each
    float* wB    = wA + NP;
    int* rankpA  = (int*)(wB + NP);              // NJC*4096 each
    int* rankpB  = rankpA + NJC * NP;
    float* rowpV = (float*)(rankpB + NJC * NP);  // 4*NP row argmax partials
    int*   rowpI = (int*)(rowpV + 4 * NP);       // 4*NP
    size_t ws_need = (size_t)((float*)(rowpI + 4 * NP) - ws) * 4;
    if (ws_size < ws_need) return;               // insufficient scratch -> fail loudly

    float* pmaxR = pconf;                        // row-stats partials alias (pre-finalize)
    float* psumR = (float*)pmi;
    float* colV  = pmax;                         // 64*NP col argmax vals (post-combine_stats)
    int*   colI  = (int*)pconf;                  // 64*NP col argmax idx (post-combine_stats)

    dim3 b256(256);

    // packed points + hc bias pre-fill
    pack_pts<<<dim3(NP / 256, 1, 6), b256, 0, stream>>>(
        ref_points, src_points, ref_points_c, src_points_c, b1,
        rp4, sp4, rcp4, scp4, o_hcr, o_hcs);

    // coarse split-K atomic proj: 512 blocks
    gemm64_atomic<<<dim3(HD / 64, NCP / 64, 16), b256, 0, stream>>>(
        ref_feats_c, src_feats_c, W1, o_hcr, o_hcs, NCP, HD, CCD, CCD / 8);

    // fine projections: 512 blocks
    gemm64<<<dim3(HD / 64, NP / 64, 2), b256, 0, stream>>>(
        ref_feats, src_feats, W2, b2, hfr, hfs, NP, HD, HD);

    // raw scores + fused row/col softmax partials (BK=32)
    gemm128_bt<<<dim3(32, 32, 1), b256, 0, stream>>>(
        hfr, hfs, o_scores, pmaxR, psumR, pmax, psum, NP, NP, HD);
    combine_stats<<<dim3(16, 1, 2), b256, 0, stream>>>(
        pmaxR, psumR, pmax, psum, rmax, rsum, cmax, csum);

    // KNN family (independent of scores)
    knn_topk<SPOTK><<<dim3(NP / 4, 1, 2), b256, 0, stream>>>(
        rp4, sp4, rp4, sp4, NP, ridx16, sidx16, nullptr, nullptr);
    knn_topk<DOWNK><<<dim3(NCP / 4, 1, 2), b256, 0, stream>>>(
        rcp4, scp4, rp4, sp4, NP, nullptr, nullptr, o_rdown, o_sdown);
    up_argmin<<<dim3(NP / 256, 1, 2), b256, 0, stream>>>(
        rp4, sp4, rcp4, scp4, o_rup, o_sup);

    // fused finalize (scores in place + row/col argmax partials) + combine
    finalize_fused<<<dim3(4, 64), b256, 0, stream>>>(
        o_scores, rmax, rsum, cmax, csum, rowpV, rowpI, colV, colI);
    argmax_combine<<<dim3(16, 1, 2), b256, 0, stream>>>(
        rowpV, rowpI, colV, colI, confr, mir, confs, mis);

    // gathers (qr/qs + spot outputs in one z-batched launch)
    gather_spot<<<dim3((NP * SPOTK) / 256, 1, 4), b256, 0, stream>>>(
        sp4, rp4, sidx16, ridx16, mir, mis, qr, qs, o_spotr, o_spots);

    // compatibility (recompute distances from packed points)
    compat_kernel<<<dim3(NP, 1, 2), b256, 0, stream>>>(
        rp4, sp4, qr, qs, o_compr, o_comps, compr, comps);

    // seeding (parallel rank pipeline)
    seed_prep<<<dim3(1, 1, 2), b256, 0, stream>>>(
        compr, comps, confr, confs, wA, wB);
    seed_rank_partial<<<dim3(NP / 256, NJC, 2), b256, 0, stream>>>(
        wA, wB, rankpA, rankpB);
    seed_scatter<<<dim3(NP / 256, 1, 2), b256, 0, stream>>>(
        rankpA, rankpB, o_seedr, o_seeds);
}

// Round 12
// 508.557 us; speedup vs baseline: 1.1733x; 1.1733x over previous
//
#include <hip/hip_runtime.h>
#include <math.h>

#define NP 4096      // N = M
#define NCP 512      // NC = MC
#define HD 256       // H and CF
#define CCD 1024     // CC
#define SPOTK 16
#define DOWNK 8
#define SEEDN 128
#define JCH 512      // seed rank j-chunk
#define NJC (NP / JCH)

// ---------------------------------------------------------------------------
// Scores GEMM + fused softmax partial stats.  (BK=32; issue-mix-bound at
// ~38% fp32 peak -- R9/R10 measured; left as-is.)
// ---------------------------------------------------------------------------
__global__ __launch_bounds__(256) void gemm128_bt(
    const float* __restrict__ A, const float* __restrict__ B,
    float* __restrict__ C,
    float* __restrict__ pmaxR, float* __restrict__ psumR,
    float* __restrict__ pmaxC, float* __restrict__ psumC,
    int M, int N, int K)
{
    const int PAD = 132;
    __shared__ float As[32 * 132];
    __shared__ float Bs[32 * 132];

    const int bm = blockIdx.y * 128, bn = blockIdx.x * 128;
    const int t = threadIdx.x;
    const int tx = t & 15, ty = t >> 4;

    float acc[2][2][4][4] = {};

    for (int k0 = 0; k0 < K; k0 += 32) {
#pragma unroll
        for (int it = 0; it < 4; it++) {
            int idx = t + it * 256;
            int row = idx >> 3, kc = (idx & 7) * 4;
            float4 va = *(const float4*)&A[(size_t)(bm + row) * K + k0 + kc];
            As[(kc + 0) * PAD + row] = va.x;
            As[(kc + 1) * PAD + row] = va.y;
            As[(kc + 2) * PAD + row] = va.z;
            As[(kc + 3) * PAD + row] = va.w;
            float4 vb = *(const float4*)&B[(size_t)(bn + row) * K + k0 + kc];
            Bs[(kc + 0) * PAD + row] = vb.x;
            Bs[(kc + 1) * PAD + row] = vb.y;
            Bs[(kc + 2) * PAD + row] = vb.z;
            Bs[(kc + 3) * PAD + row] = vb.w;
        }
        __syncthreads();
#pragma unroll
        for (int kk = 0; kk < 32; kk++) {
            float4 a0 = *(const float4*)&As[kk * PAD + ty * 4];
            float4 a1 = *(const float4*)&As[kk * PAD + ty * 4 + 64];
            float4 b0 = *(const float4*)&Bs[kk * PAD + tx * 4];
            float4 b1 = *(const float4*)&Bs[kk * PAD + tx * 4 + 64];
            float ar[2][4] = {{a0.x, a0.y, a0.z, a0.w}, {a1.x, a1.y, a1.z, a1.w}};
            float br[2][4] = {{b0.x, b0.y, b0.z, b0.w}, {b1.x, b1.y, b1.z, b1.w}};
#pragma unroll
            for (int qr = 0; qr < 2; qr++)
#pragma unroll
                for (int qc = 0; qc < 2; qc++)
#pragma unroll
                    for (int i = 0; i < 4; i++)
#pragma unroll
                        for (int j = 0; j < 4; j++)
                            acc[qr][qc][i][j] = fmaf(ar[qr][i], br[qc][j], acc[qr][qc][i][j]);
        }
        __syncthreads();
    }

    // C write (unchanged order -> bitwise-identical scores)
#pragma unroll
    for (int qr = 0; qr < 2; qr++)
#pragma unroll
        for (int i = 0; i < 4; i++) {
            int m = bm + qr * 64 + ty * 4 + i;
#pragma unroll
            for (int qc = 0; qc < 2; qc++) {
                int n = bn + qc * 64 + tx * 4;
                float4 v = make_float4(acc[qr][qc][i][0], acc[qr][qc][i][1],
                                       acc[qr][qc][i][2], acc[qr][qc][i][3]);
                *(float4*)&C[(size_t)m * N + n] = v;
            }
        }

    // ---- row partials ----
#pragma unroll
    for (int qr = 0; qr < 2; qr++)
#pragma unroll
        for (int i = 0; i < 4; i++) {
            float m = -INFINITY;
#pragma unroll
            for (int qc = 0; qc < 2; qc++)
#pragma unroll
                for (int j = 0; j < 4; j++) m = fmaxf(m, acc[qr][qc][i][j]);
            float s = 0.f;
#pragma unroll
            for (int qc = 0; qc < 2; qc++)
#pragma unroll
                for (int j = 0; j < 4; j++) s += expf(acc[qr][qc][i][j] - m);
#pragma unroll
            for (int off = 1; off < 16; off <<= 1) {
                float om = __shfl_xor(m, off), os = __shfl_xor(s, off);
                float Mx = fmaxf(m, om);
                s = s * expf(m - Mx) + os * expf(om - Mx);
                m = Mx;
            }
            if (tx == 0) {
                int r = bm + qr * 64 + ty * 4 + i;
                pmaxR[(size_t)blockIdx.x * NP + r] = m;
                psumR[(size_t)blockIdx.x * NP + r] = s;
            }
        }

    // ---- col partials ----
    float* colm = As;
    float* cols_ = Bs;
#pragma unroll
    for (int qc = 0; qc < 2; qc++)
#pragma unroll
        for (int j = 0; j < 4; j++) {
            float m = -INFINITY;
#pragma unroll
            for (int qr = 0; qr < 2; qr++)
#pragma unroll
                for (int i = 0; i < 4; i++) m = fmaxf(m, acc[qr][qc][i][j]);
            float s = 0.f;
#pragma unroll
            for (int qr = 0; qr < 2; qr++)
#pragma unroll
                for (int i = 0; i < 4; i++) s += expf(acc[qr][qc][i][j] - m);
#pragma unroll
            for (int off = 16; off < 64; off <<= 1) {
                float om = __shfl_xor(m, off), os = __shfl_xor(s, off);
                float Mx = fmaxf(m, om);
                s = s * expf(m - Mx) + os * expf(om - Mx);
                m = Mx;
            }
            if ((ty & 3) == 0) {
                int w = ty >> 2, c = qc * 64 + tx * 4 + j;
                colm[w * 132 + c] = m;
                cols_[w * 132 + c] = s;
            }
        }
    __syncthreads();
    if (t < 128) {
        int c = t;
        float m = colm[c], s = cols_[c];
#pragma unroll
        for (int w = 1; w < 4; w++) {
            float om = colm[w * 132 + c], os = cols_[w * 132 + c];
            float Mx = fmaxf(m, om);
            s = s * expf(m - Mx) + os * expf(om - Mx);
            m = Mx;
        }
        pmaxC[(size_t)blockIdx.y * NP + bn + c] = m;
        psumC[(size_t)blockIdx.y * NP + bn + c] = s;
    }
}

// Partial-stats combine over 32 chunks: out(max, rescaled-sum). z-batched.
__global__ __launch_bounds__(256) void combine_stats(
    const float* __restrict__ pmaxA, const float* __restrict__ psumA,
    const float* __restrict__ pmaxB, const float* __restrict__ psumB,
    float* omaxA, float* osumA, float* omaxB, float* osumB)
{
    const float* pmax = blockIdx.z ? pmaxB : pmaxA;
    const float* psum = blockIdx.z ? psumB : psumA;
    float* omax       = blockIdx.z ? omaxB : omaxA;
    float* osum       = blockIdx.z ? osumB : osumA;
    int m = blockIdx.x * 256 + threadIdx.x;
    float mx = -INFINITY;
    for (int c = 0; c < 32; c++) mx = fmaxf(mx, pmax[(size_t)c * NP + m]);
    float sum = 0.f;
    for (int c = 0; c < 32; c++) sum += psum[(size_t)c * NP + m] * expf(pmax[(size_t)c * NP + m] - mx);
    omax[m] = mx; osum[m] = sum;
}

// ---------------------------------------------------------------------------
// Projection GEMM, 64x64 tile, 256 threads, 4x4 microtile: C = A @ B (+bias).
// ---------------------------------------------------------------------------
__global__ __launch_bounds__(256) void gemm64(
    const float* __restrict__ A0, const float* __restrict__ A1,
    const float* __restrict__ B, const float* __restrict__ bias,
    float* __restrict__ C0, float* __restrict__ C1,
    int M, int N, int K)
{
    const float* A = blockIdx.z ? A1 : A0;
    float* C = blockIdx.z ? C1 : C0;

    const int PAD = 68;
    __shared__ float As[16 * 68];
    __shared__ float Bs[16 * 68];

    const int bm = blockIdx.y * 64, bn = blockIdx.x * 64;
    const int t = threadIdx.x;
    const int tx = t & 15, ty = t >> 4;

    float acc[4][4] = {};

    for (int k0 = 0; k0 < K; k0 += 16) {
        {
            int row = t >> 2, kc = (t & 3) * 4;
            float4 v = *(const float4*)&A[(size_t)(bm + row) * K + k0 + kc];
            As[(kc + 0) * PAD + row] = v.x;
            As[(kc + 1) * PAD + row] = v.y;
            As[(kc + 2) * PAD + row] = v.z;
            As[(kc + 3) * PAD + row] = v.w;
        }
        {
            int k = t >> 4, n4 = (t & 15) * 4;
            float4 v = *(const float4*)&B[(size_t)(k0 + k) * N + bn + n4];
            *(float4*)&Bs[k * PAD + n4] = v;
        }
        __syncthreads();
#pragma unroll
        for (int kk = 0; kk < 16; kk++) {
            float4 a4 = *(const float4*)&As[kk * PAD + ty * 4];
            float4 b4 = *(const float4*)&Bs[kk * PAD + tx * 4];
            float ar[4] = {a4.x, a4.y, a4.z, a4.w};
            float br[4] = {b4.x, b4.y, b4.z, b4.w};
#pragma unroll
            for (int i = 0; i < 4; i++)
#pragma unroll
                for (int j = 0; j < 4; j++)
                    acc[i][j] = fmaf(ar[i], br[j], acc[i][j]);
        }
        __syncthreads();
    }
    float4 b4 = *(const float4*)&bias[bn + tx * 4];
#pragma unroll
    for (int i = 0; i < 4; i++) {
        int m = bm + ty * 4 + i;
        float4 v = make_float4(acc[i][0] + b4.x, acc[i][1] + b4.y,
                               acc[i][2] + b4.z, acc[i][3] + b4.w);
        *(float4*)&C[(size_t)m * N + bn + tx * 4] = v;
    }
}

// Split-K variant: z = pair*8 + ks; atomicAdd 64x64 partials into C
// (pre-initialized with bias via pack_pts z=4/5).
__global__ __launch_bounds__(256) void gemm64_atomic(
    const float* __restrict__ A0, const float* __restrict__ A1,
    const float* __restrict__ B,
    float* __restrict__ C0, float* __restrict__ C1,
    int M, int N, int K, int KCH)
{
    int pair = blockIdx.z >> 3, ks = blockIdx.z & 7;
    const float* A = pair ? A1 : A0;
    float* C = pair ? C1 : C0;

    const int PAD = 68;
    __shared__ float As[16 * 68];
    __shared__ float Bs[16 * 68];

    const int bm = blockIdx.y * 64, bn = blockIdx.x * 64;
    const int t = threadIdx.x;
    const int tx = t & 15, ty = t >> 4;
    const int kbeg = ks * KCH, kend = kbeg + KCH;

    float acc[4][4] = {};

    for (int k0 = kbeg; k0 < kend; k0 += 16) {
        {
            int row = t >> 2, kc = (t & 3) * 4;
            float4 v = *(const float4*)&A[(size_t)(bm + row) * K + k0 + kc];
            As[(kc + 0) * PAD + row] = v.x;
            As[(kc + 1) * PAD + row] = v.y;
            As[(kc + 2) * PAD + row] = v.z;
            As[(kc + 3) * PAD + row] = v.w;
        }
        {
            int k = t >> 4, n4 = (t & 15) * 4;
            float4 v = *(const float4*)&B[(size_t)(k0 + k) * N + bn + n4];
            *(float4*)&Bs[k * PAD + n4] = v;
        }
        __syncthreads();
#pragma unroll
        for (int kk = 0; kk < 16; kk++) {
            float4 a4 = *(const float4*)&As[kk * PAD + ty * 4];
            float4 b4 = *(const float4*)&Bs[kk * PAD + tx * 4];
            float ar[4] = {a4.x, a4.y, a4.z, a4.w};
            float br[4] = {b4.x, b4.y, b4.z, b4.w};
#pragma unroll
            for (int i = 0; i < 4; i++)
#pragma unroll
                for (int j = 0; j < 4; j++)
                    acc[i][j] = fmaf(ar[i], br[j], acc[i][j]);
        }
        __syncthreads();
    }
#pragma unroll
    for (int i = 0; i < 4; i++) {
        int m = bm + ty * 4 + i;
#pragma unroll
        for (int j = 0; j < 4; j++)
            atomicAdd(&C[(size_t)m * N + bn + tx * 4 + j], acc[i][j]);
    }
}

// ---------------------------------------------------------------------------
// Pack points (z=0..3) + hc bias pre-fill (z=4,5; grid-stride).
// ---------------------------------------------------------------------------
__global__ void pack_pts(const float* __restrict__ p0, const float* __restrict__ p1,
                         const float* __restrict__ p2, const float* __restrict__ p3,
                         const float* __restrict__ b1,
                         float4* o0, float4* o1, float4* o2, float4* o3,
                         float* __restrict__ o_hcr, float* __restrict__ o_hcs)
{
    int z = blockIdx.z;
    if (z >= 4) {
        float* o = (z == 4) ? o_hcr : o_hcs;
        for (int idx = blockIdx.x * 256 + threadIdx.x; idx < NCP * HD; idx += 16 * 256)
            o[idx] = b1[idx & (HD - 1)];
        return;
    }
    const float* p = (z == 0) ? p0 : (z == 1) ? p1 : (z == 2) ? p2 : p3;
    float4* o      = (z == 0) ? o0 : (z == 1) ? o1 : (z == 2) ? o2 : o3;
    int n = (z < 2) ? NP : NCP;
    int i = blockIdx.x * 256 + threadIdx.x;
    if (i >= n) return;
    float x = p[i * 3], y = p[i * 3 + 1], zz = p[i * 3 + 2];
    o[i] = make_float4(x, y, zz, x * x + y * y + zz * zz);
}

// ---------------------------------------------------------------------------
// Final scores (in place, float4) + per-row max/argmax.  Row per block;
// thread t handles cols {chunk*1024 + t*4 .. +3}, ascending -> strict >
// keeps first occurrence; block lex reduce is partition-independent.
// ---------------------------------------------------------------------------
__global__ __launch_bounds__(256) void finalize_rows(float* __restrict__ s,
    const float* __restrict__ rmax, const float* __restrict__ rsum,
    const float* __restrict__ cmax, const float* __restrict__ csum,
    float* __restrict__ confr, int* __restrict__ mir)
{
    int n = blockIdx.x;
    float rm = rmax[n], rs = rsum[n];
    size_t base = (size_t)n * NP;
    float best = -INFINITY; int bi = 0x7fffffff;
    for (int ch = 0; ch < 4; ch++) {
        int c = ch * 1024 + threadIdx.x * 4;
        float4 v = *(const float4*)&s[base + c];
        float4 cm = *(const float4*)&cmax[c];
        float4 cs = *(const float4*)&csum[c];
        float sc0 = (expf(v.x - rm) / rs) * (expf(v.x - cm.x) / cs.x);
        float sc1 = (expf(v.y - rm) / rs) * (expf(v.y - cm.y) / cs.y);
        float sc2 = (expf(v.z - rm) / rs) * (expf(v.z - cm.z) / cs.z);
        float sc3 = (expf(v.w - rm) / rs) * (expf(v.w - cm.w) / cs.w);
        *(float4*)&s[base + c] = make_float4(sc0, sc1, sc2, sc3);
        if (sc0 > best) { best = sc0; bi = c; }
        if (sc1 > best) { best = sc1; bi = c + 1; }
        if (sc2 > best) { best = sc2; bi = c + 2; }
        if (sc3 > best) { best = sc3; bi = c + 3; }
    }
    __shared__ float rv[256]; __shared__ int ri[256];
    rv[threadIdx.x] = best; ri[threadIdx.x] = bi; __syncthreads();
    for (int off = 128; off; off >>= 1) {
        if (threadIdx.x < off) {
            float v2 = rv[threadIdx.x + off]; int i2 = ri[threadIdx.x + off];
            if (v2 > rv[threadIdx.x] || (v2 == rv[threadIdx.x] && i2 < ri[threadIdx.x])) {
                rv[threadIdx.x] = v2; ri[threadIdx.x] = i2;
            }
        }
        __syncthreads();
    }
    if (threadIdx.x == 0) { confr[n] = rv[0]; mir[n] = ri[0]; }
}

// Column max/argmax over final scores (chunked, float4: thread = 4 cols)
__global__ __launch_bounds__(256) void col_argmax_partial(const float* __restrict__ s,
                                                          float* pconf, int* pmi)
{
    int m = (blockIdx.x * 256 + threadIdx.x) * 4;
    int n0 = blockIdx.y * 128;
    float4 best = make_float4(-INFINITY, -INFINITY, -INFINITY, -INFINITY);
    int4 bi = make_int4(0, 0, 0, 0);
    for (int n = n0; n < n0 + 128; n++) {
        float4 v = *(const float4*)&s[(size_t)n * NP + m];
        if (v.x > best.x) { best.x = v.x; bi.x = n; }
        if (v.y > best.y) { best.y = v.y; bi.y = n; }
        if (v.z > best.z) { best.z = v.z; bi.z = n; }
        if (v.w > best.w) { best.w = v.w; bi.w = n; }
    }
    *(float4*)&pconf[(size_t)blockIdx.y * NP + m] = best;
    *(int4*)&pmi[(size_t)blockIdx.y * NP + m] = bi;
}

__global__ __launch_bounds__(256) void col_argmax_combine(const float* __restrict__ pconf,
                                                          const int* __restrict__ pmi,
                                                          float* confs, int* mis)
{
    int m = blockIdx.x * 256 + threadIdx.x;
    float best = -INFINITY; int bi = 0;
    for (int c = 0; c < 32; c++) {              // ascending chunks -> first max wins
        float v = pconf[(size_t)c * NP + m];
        if (v > best) { best = v; bi = pmi[(size_t)c * NP + m]; }
    }
    confs[m] = best; mis[m] = bi;
}

// Gathers after argmax (z-batched 0..3)
__global__ void gather_spot(
    const float4* __restrict__ sp4, const float4* __restrict__ rp4,
    const int* __restrict__ sidx16, const int* __restrict__ ridx16,
    const int* __restrict__ mir, const int* __restrict__ mis,
    float4* __restrict__ qr, float4* __restrict__ qs,
    float* __restrict__ o_spotr, float* __restrict__ o_spots)
{
    int z = blockIdx.z;
    int t = blockIdx.x * 256 + threadIdx.x;
    if (z < 2) {
        if (t >= NP) return;
        const float4* p4 = z ? rp4 : sp4;
        const int*    mi = z ? mis : mir;
        float4*       q  = z ? qs : qr;
        q[t] = p4[mi[t]];
    } else {
        int n = t >> 4, k = t & 15;
        const int* idx16 = (z == 2) ? sidx16 : ridx16;
        const int* mi    = (z == 2) ? mir : mis;
        float* outp      = (z == 2) ? o_spotr : o_spots;
        outp[t] = (float)idx16[(size_t)mi[n] * SPOTK + k];
    }
}

// compat[n] = mean_j relu(1 - |d(base_n, base_j) - d(q_n, q_j)| / 3)   (z-batched)
__global__ __launch_bounds__(256) void compat_kernel(
    const float4* __restrict__ baseA, const float4* __restrict__ baseB,
    const float4* __restrict__ qA, const float4* __restrict__ qB,
    float* __restrict__ o1A, float* __restrict__ o1B,
    float* __restrict__ o2A, float* __restrict__ o2B)
{
    const float4* base = blockIdx.z ? baseB : baseA;
    const float4* q    = blockIdx.z ? qB : qA;
    float* out1        = blockIdx.z ? o1B : o1A;
    float* out2        = blockIdx.z ? o2B : o2A;
    int n = blockIdx.x;
    float4 b = base[n];
    float4 a = q[n];
    float sum = 0.f;
    for (int j = threadIdx.x; j < NP; j += 256) {
        float4 p = base[j];
        float rt = b.x * p.x + b.y * p.y + b.z * p.z;
        float rd = (b.w - 2.f * rt) + p.w;
        float4 qj = q[j];
        float st = a.x * qj.x + a.y * qj.y + a.z * qj.z;
        float sd = (a.w - 2.f * st) + qj.w;
        float c = 1.f - fabsf(rd - sd) / 3.0f;
        sum += fmaxf(c, 0.f);
    }
    __shared__ float red[256];
    red[threadIdx.x] = sum; __syncthreads();
    for (int off = 128; off; off >>= 1) {
        if (threadIdx.x < off) red[threadIdx.x] += red[threadIdx.x + off];
        __syncthreads();
    }
    if (threadIdx.x == 0) { float c = red[0] * (1.0f / NP); out1[n] = c; out2[n] = c; }
}

// ---------------------------------------------------------------------------
// Seeding, parallel rank pipeline (exact jax.lax.top_k order/ties).
// ---------------------------------------------------------------------------
__global__ __launch_bounds__(256) void seed_prep(
    const float* __restrict__ compatA, const float* __restrict__ compatB,
    const float* __restrict__ confA, const float* __restrict__ confB,
    float* __restrict__ wA, float* __restrict__ wB)
{
    const float* compat = blockIdx.z ? compatB : compatA;
    const float* conf   = blockIdx.z ? confB : confA;
    float* w            = blockIdx.z ? wB : wA;
    __shared__ float red[256];
    int tid = threadIdx.x;
    float mx = -INFINITY;
    for (int j = tid; j < NP; j += 256) mx = fmaxf(mx, compat[j]);
    red[tid] = mx; __syncthreads();
    for (int off = 128; off; off >>= 1) {
        if (tid < off) red[tid] = fmaxf(red[tid], red[tid + off]);
        __syncthreads();
    }
    float thr = red[0] * 0.5f;
    for (int j = tid; j < NP; j += 256) {
        float c = compat[j];
        w[j] = (c < thr) ? conf[j] * c : 0.0f;
    }
}

__global__ __launch_bounds__(256) void seed_rank_partial(
    const float* __restrict__ wA, const float* __restrict__ wB,
    int* __restrict__ rankpA, int* __restrict__ rankpB)
{
    const float* w = blockIdx.z ? wB : wA;
    int* rankp     = blockIdx.z ? rankpB : rankpA;
    int tid = threadIdx.x;
    int jc = blockIdx.y;

    __shared__ float4 wj[JCH / 4];
    if (tid < JCH / 4) wj[tid] = ((const float4*)w)[jc * (JCH / 4) + tid];
    __syncthreads();

    int i = blockIdx.x * 256 + tid;
    float wi = w[i];
    int jbase = jc * JCH;
    int r0 = 0, r1 = 0, r2 = 0, r3 = 0;
#pragma unroll 4
    for (int j4 = 0; j4 < JCH / 4; j4++) {
        float4 v = wj[j4];
        int j = jbase + j4 * 4;
        r0 += (v.x > wi || (v.x == wi && (j    ) < i));
        r1 += (v.y > wi || (v.y == wi && (j + 1) < i));
        r2 += (v.z > wi || (v.z == wi && (j + 2) < i));
        r3 += (v.w > wi || (v.w == wi && (j + 3) < i));
    }
    rankp[(size_t)jc * NP + i] = (r0 + r1) + (r2 + r3);
}

__global__ __launch_bounds__(256) void seed_scatter(
    const int* __restrict__ rankpA, const int* __restrict__ rankpB,
    float* __restrict__ outA, float* __restrict__ outB)
{
    const int* rankp = blockIdx.z ? rankpB : rankpA;
    float* outp      = blockIdx.z ? outB : outA;
    int i = blockIdx.x * 256 + threadIdx.x;
    int r = 0;
#pragma unroll
    for (int jc = 0; jc < NJC; jc++) r += rankp[(size_t)jc * NP + i];
    if (r < SEEDN) outp[r] = (float)i;
}

// ---------------------------------------------------------------------------
// Wave-wide bitonic sorts via shfl_xor (64 lanes, zero barriers).
// ---------------------------------------------------------------------------
__device__ __forceinline__ void bitonic64_val(float& d, int lane)
{
#pragma unroll
    for (int k = 2; k <= 64; k <<= 1)
#pragma unroll
        for (int j = k >> 1; j > 0; j >>= 1) {
            float od = __shfl_xor(d, j);
            bool lower = ((lane & j) == 0);
            bool asc   = ((lane & k) == 0);
            bool take = (lower == asc) ? (od < d) : (d < od);
            d = take ? od : d;
        }
}

__device__ __forceinline__ void bitonic64_lex(float& d, int& i, int lane)
{
#pragma unroll
    for (int k = 2; k <= 64; k <<= 1)
#pragma unroll
        for (int j = k >> 1; j > 0; j >>= 1) {
            float od = __shfl_xor(d, j);
            int   oi = __shfl_xor(i, j);
            bool lower = ((lane & j) == 0);
            bool asc   = ((lane & k) == 0);
            bool less = (od < d) || (od == d && oi < i);
            bool gtr  = (d < od) || (d == od && i < oi);
            bool take = (lower == asc) ? less : gtr;
            d = take ? od : d;
            i = take ? oi : i;
        }
}

template<int KSEL>
__device__ __forceinline__ void merge_chunk(float& run_d, int& run_i,
                                            float cd, int ci, int lane)
{
    bitonic64_lex(cd, ci, lane);
    int src = lane - KSEL;
    int s2 = (src >= 0 && src < KSEL) ? src : 0;
    float cd2 = __shfl(cd, s2);
    int   ci2 = __shfl(ci, s2);
    float nd = (lane < KSEL) ? run_d : ((lane < 2 * KSEL) ? cd2 : INFINITY);
    int   ni = (lane < KSEL) ? run_i : ((lane < 2 * KSEL) ? ci2 : 0x7fffffff);
    bitonic64_lex(nd, ni, lane);
    run_d = nd; run_i = ni;
}

// ---------------------------------------------------------------------------
// KNN top-K via threshold pre-filter (packed float4 points).
// ---------------------------------------------------------------------------
template<int KSEL>
__global__ __launch_bounds__(256) void knn_topk(
    const float4* __restrict__ rowA, const float4* __restrict__ rowB,
    const float4* __restrict__ colA, const float4* __restrict__ colB,
    int ncols,
    int* __restrict__ outiA, int* __restrict__ outiB,
    float* __restrict__ outfA, float* __restrict__ outfB)
{
    const float4* rowp = blockIdx.z ? rowB : rowA;
    const float4* colp = blockIdx.z ? colB : colA;
    int* outi = blockIdx.z ? outiB : outiA;
    float* outf = blockIdx.z ? outfB : outfA;

    int wid = threadIdx.x >> 6, lane = threadIdx.x & 63;
    int r = blockIdx.x * 4 + wid;

    float4 p = rowp[r];

    float mn = INFINITY;
    for (int j0 = 0; j0 < ncols; j0 += 64) {
        float4 c = colp[j0 + lane];
        float t = p.x * c.x + p.y * c.y + p.z * c.z;
        float d = (p.w - 2.f * t) + c.w;
        mn = fminf(mn, d);
    }
    bitonic64_val(mn, lane);
    float T = __shfl(mn, KSEL - 1) + 1e-4f;

    __shared__ float qd[4][256];
    __shared__ int   qi[4][256];
    int cnt = 0; bool ovf = false;
    for (int j0 = 0; j0 < ncols; j0 += 64) {
        int j = j0 + lane;
        float4 c = colp[j];
        float t = p.x * c.x + p.y * c.y + p.z * c.z;
        float d = (p.w - 2.f * t) + c.w;
        bool keep = (d <= T);
        unsigned long long mask = __ballot(keep);
        int nsel = __popcll(mask);
        if (cnt + nsel > 256) { ovf = true; break; }
        if (keep) {
            int pos = cnt + (int)__popcll(mask & ((1ull << lane) - 1ull));
            qd[wid][pos] = d; qi[wid][pos] = j;
        }
        cnt += nsel;
    }

    float run_d = INFINITY; int run_i = 0x7fffffff;
    if (!ovf) {
        for (int c = 0; c < cnt; c += 64) {
            int idx = c + lane;
            float cd = (idx < cnt) ? qd[wid][idx] : INFINITY;
            int   ci = (idx < cnt) ? qi[wid][idx] : 0x7fffffff;
            merge_chunk<KSEL>(run_d, run_i, cd, ci, lane);
        }
    } else {
        for (int j0 = 0; j0 < ncols; j0 += 64) {
            int j = j0 + lane;
            float4 c = colp[j];
            float t = p.x * c.x + p.y * c.y + p.z * c.z;
            float d = (p.w - 2.f * t) + c.w;
            merge_chunk<KSEL>(run_d, run_i, d, j, lane);
        }
    }

    if (lane < KSEL) {
        if (outi) outi[(size_t)r * KSEL + lane] = run_i;
        else      outf[(size_t)r * KSEL + lane] = (float)run_i;
    }
}

// argmin over the 512 coarse points per fine point (first-min index), z-batched
__global__ __launch_bounds__(256) void up_argmin(
    const float4* __restrict__ ptsA, const float4* __restrict__ ptsB,
    const float4* __restrict__ ptscA, const float4* __restrict__ ptscB,
    float* __restrict__ outA, float* __restrict__ outB)
{
    const float4* pts   = blockIdx.z ? ptsB : ptsA;
    const float4* pts_c = blockIdx.z ? ptscB : ptscA;
    float* out_f        = blockIdx.z ? outB : outA;
    __shared__ float4 cp[NCP];
    for (int c = threadIdx.x; c < NCP; c += 256) cp[c] = pts_c[c];
    __syncthreads();
    int n = blockIdx.x * 256 + threadIdx.x;
    float4 p = pts[n];
    float best = INFINITY; int bi = 0;
    for (int c = 0; c < NCP; c++) {
        float4 q = cp[c];
        float t = p.x * q.x + p.y * q.y + p.z * q.z;
        float d = (p.w - 2.f * t) + q.w;
        if (d < best) { best = d; bi = c; }
    }
    out_f[n] = (float)bi;
}

// ---------------------------------------------------------------------------
extern "C" void kernel_launch(void* const* d_in, const int* in_sizes, int n_in,
                              void* d_out, int out_size, void* d_ws, size_t ws_size,
                              hipStream_t stream)
{
    const float* ref_points   = (const float*)d_in[0];
    const float* src_points   = (const float*)d_in[1];
    const float* ref_feats    = (const float*)d_in[2];
    const float* src_feats    = (const float*)d_in[3];
    const float* ref_points_c = (const float*)d_in[4];
    const float* src_points_c = (const float*)d_in[5];
    const float* ref_feats_c  = (const float*)d_in[6];
    const float* src_feats_c  = (const float*)d_in[7];
    const float* W1 = (const float*)d_in[8];
    const float* b1 = (const float*)d_in[9];
    const float* W2 = (const float*)d_in[10];
    const float* b2 = (const float*)d_in[11];

    // ---- d_out layout (all float32; indices written as float) ----
    float* out = (float*)d_out;
    float* o_scores = out;                       // 4096*4096
    float* o_compr  = o_scores + (size_t)NP * NP;
    float* o_comps  = o_compr + NP;
    float* o_seedr  = o_comps + NP;
    float* o_seeds  = o_seedr + SEEDN;
    float* o_spotr  = o_seeds + SEEDN;           // 4096*16
    float* o_spots  = o_spotr + (size_t)NP * SPOTK;
    float* o_hcr    = o_spots + (size_t)NP * SPOTK;   // 512*256
    float* o_hcs    = o_hcr + (size_t)NCP * HD;
    float* o_rup    = o_hcs + (size_t)NCP * HD;  // 4096
    float* o_sup    = o_rup + NP;
    float* o_rdown  = o_sup + NP;                // 512*8
    float* o_sdown  = o_rdown + (size_t)NCP * DOWNK;

    // ---- workspace layout ----
    float* ws = (float*)d_ws;
    float* hfr   = ws;                           // 4096*256
    float* hfs   = hfr + (size_t)NP * HD;
    float* rmax  = hfs + (size_t)NP * HD;        // 4096 each
    float* rsum  = rmax + NP;
    float* cmax  = rsum + NP;
    float* csum  = cmax + NP;
    float* confr = csum + NP;
    float* confs = confr + NP;
    float* compr = confs + NP;
    float* comps = compr + NP;
    int*   mir   = (int*)(comps + NP);
    int*   mis   = mir + NP;
    float* pmax  = (float*)(mis + NP);           // 32*NP (col stats partials)
    float* psum  = pmax + 32 * NP;
    float* pconf = psum + 32 * NP;               // col argmax partials; ALSO row
    int*   pmi   = (int*)(pconf + 32 * NP);      //   stats partials (disjoint lifetime)
    float4* qr   = (float4*)(pmi + 32 * NP);     // 4096 float4 each
    float4* qs   = qr + NP;
    int* ridx16  = (int*)(qs + NP);              // 4096*16 each
    int* sidx16  = ridx16 + (size_t)NP * SPOTK;
    float4* rp4  = (float4*)(sidx16 + (size_t)NP * SPOTK);  // packed points
    float4* sp4  = rp4 + NP;
    float4* rcp4 = sp4 + NP;
    float4* scp4 = rcp4 + NCP;
    float* wA    = (float*)(scp4 + NCP);         // seed weights, 4096 each
    float* wB    = wA + NP;
    int* rankpA  = (int*)(wB + NP);              // NJC*4096 each
    int* rankpB  = rankpA + NJC * NP;
    size_t ws_need = (size_t)((float*)(rankpB + NJC * NP) - ws) * 4;
    if (ws_size < ws_need) return;               // insufficient scratch -> fail loudly

    float* pmaxR = pconf;                        // row-stats partials alias
    float* psumR = (float*)pmi;                  //   (consumed before col_argmax)

    dim3 b256(256);

    // packed points + hc bias pre-fill
    pack_pts<<<dim3(NP / 256, 1, 6), b256, 0, stream>>>(
        ref_points, src_points, ref_points_c, src_points_c, b1,
        rp4, sp4, rcp4, scp4, o_hcr, o_hcs);

    // coarse split-K atomic proj: 512 blocks
    gemm64_atomic<<<dim3(HD / 64, NCP / 64, 16), b256, 0, stream>>>(
        ref_feats_c, src_feats_c, W1, o_hcr, o_hcs, NCP, HD, CCD, CCD / 8);

    // fine projections: 512 blocks
    gemm64<<<dim3(HD / 64, NP / 64, 2), b256, 0, stream>>>(
        ref_feats, src_feats, W2, b2, hfr, hfs, NP, HD, HD);

    // raw scores + fused row/col softmax partials (BK=32)
    gemm128_bt<<<dim3(32, 32, 1), b256, 0, stream>>>(
        hfr, hfs, o_scores, pmaxR, psumR, pmax, psum, NP, NP, HD);
    combine_stats<<<dim3(16, 1, 2), b256, 0, stream>>>(
        pmaxR, psumR, pmax, psum, rmax, rsum, cmax, csum);

    // KNN family (independent of scores)
    knn_topk<SPOTK><<<dim3(NP / 4, 1, 2), b256, 0, stream>>>(
        rp4, sp4, rp4, sp4, NP, ridx16, sidx16, nullptr, nullptr);
    knn_topk<DOWNK><<<dim3(NCP / 4, 1, 2), b256, 0, stream>>>(
        rcp4, scp4, rp4, sp4, NP, nullptr, nullptr, o_rdown, o_sdown);
    up_argmin<<<dim3(NP / 256, 1, 2), b256, 0, stream>>>(
        rp4, sp4, rcp4, scp4, o_rup, o_sup);

    // dual softmax finalize + argmaxes
    finalize_rows<<<NP, b256, 0, stream>>>(o_scores, rmax, rsum, cmax, csum, confr, mir);
    col_argmax_partial<<<dim3(4, 32), b256, 0, stream>>>(o_scores, pconf, pmi);
    col_argmax_combine<<<16, b256, 0, stream>>>(pconf, pmi, confs, mis);

    // gathers (qr/qs + spot outputs in one z-batched launch)
    gather_spot<<<dim3((NP * SPOTK) / 256, 1, 4), b256, 0, stream>>>(
        sp4, rp4, sidx16, ridx16, mir, mis, qr, qs, o_spotr, o_spots);

    // compatibility (recompute distances from packed points)
    compat_kernel<<<dim3(NP, 1, 2), b256, 0, stream>>>(
        rp4, sp4, qr, qs, o_compr, o_comps, compr, comps);

    // seeding (parallel rank pipeline)
    seed_prep<<<dim3(1, 1, 2), b256, 0, stream>>>(
        compr, comps, confr, confs, wA, wB);
    seed_rank_partial<<<dim3(NP / 256, NJC, 2), b256, 0, stream>>>(
        wA, wB, rankpA, rankpB);
    seed_scatter<<<dim3(NP / 256, 1, 2), b256, 0, stream>>>(
        rankpA, rankpB, o_seedr, o_seeds);
}